// Round 11
// baseline (650.770 us; speedup 1.0000x reference)
//
#include <hip/hip_runtime.h>
#include <hip/hip_bf16.h>

// Problem constants
#define TT   256
#define BB   1024
#define OBS  64
#define HH   128
#define AA   32
#define NN   (TT*BB)          // 262144

typedef __bf16 bf16x8 __attribute__((ext_vector_type(8)));
typedef __bf16 bf16x4 __attribute__((ext_vector_type(4)));
typedef float  f32x4  __attribute__((ext_vector_type(4)));

__device__ __forceinline__ float sigmoidf_(float x) {
    return 1.0f / (1.0f + __expf(-x));
}
__device__ __forceinline__ float tanhf_(float x) {
    float ax = fabsf(x);
    float e  = __expf(-2.0f * ax);
    float t  = (1.0f - e) / (1.0f + e);
    return copysignf(t, x);
}
__device__ __forceinline__ __hip_bfloat16 f2b(float v) { return __float2bfloat16(v); }
__device__ __forceinline__ bf16x8 ldb(const __hip_bfloat16* p) {
    return *reinterpret_cast<const bf16x8*>(p);
}
__device__ __forceinline__ f32x4 mm16(bf16x8 a, bf16x8 b, f32x4 c) {
    return __builtin_amdgcn_mfma_f32_16x16x32_bf16(a, b, c, 0, 0, 0);
}

// ---------------------------------------------------------------------------
// Kernel 1 (MFMA bf16): hidden = relu(relu(x@W1+b1)@W2+b2);
//   xg = hidden@w_ih.T + (b_ih+b_hh) -> bf16 [N][128][4] (gate-interleaved:
//   column = un*4 + gt, so the LSTM reads all 4 gates of a unit as one 8B load)
// ---------------------------------------------------------------------------
__global__ __launch_bounds__(512) void trunk_kernel(
    const float* __restrict__ x,
    const float* __restrict__ W1, const float* __restrict__ b1,
    const float* __restrict__ W2, const float* __restrict__ b2,
    const float* __restrict__ w_ih,
    const float* __restrict__ b_ih, const float* __restrict__ b_hh,
    __hip_bfloat16* __restrict__ xg)
{
    __shared__ __align__(16) char smem[109568];
    __hip_bfloat16 (*xb)[72]    = (__hip_bfloat16(*)[72])(smem);
    __hip_bfloat16 (*W1T)[72]   = (__hip_bfloat16(*)[72])(smem + 18432);
    __hip_bfloat16 (*W2T)[136]  = (__hip_bfloat16(*)[136])(smem);
    __hip_bfloat16 (*h1b)[136]  = (__hip_bfloat16(*)[136])(smem + 36864);
    __hip_bfloat16 (*h2b)[136]  = (__hip_bfloat16(*)[136])(smem + 71680);
    __hip_bfloat16 (*wihb)[136] = (__hip_bfloat16(*)[136])(smem);
    float* sb1  = (float*)(smem + 106496);
    float* sb2  = sb1 + 128;
    float* sbih = sb2 + 128;

    const int tid  = threadIdx.x;
    const int lane = tid & 63;
    const int w    = tid >> 6;
    const int m0   = w * 16;
    const int lm   = lane & 15;
    const int lk   = (lane >> 4) * 8;
    const size_t r0 = (size_t)blockIdx.x * 128;

    {
        int row = tid >> 2, seg = tid & 3;
        const float4* xs = (const float4*)(x + (r0 + row) * OBS + seg * 16);
        float4 v0 = xs[0], v1 = xs[1], v2 = xs[2], v3 = xs[3];
        union { bf16x8 v[2]; __hip_bfloat16 h[16]; } u;
        u.h[0]=f2b(v0.x); u.h[1]=f2b(v0.y); u.h[2]=f2b(v0.z); u.h[3]=f2b(v0.w);
        u.h[4]=f2b(v1.x); u.h[5]=f2b(v1.y); u.h[6]=f2b(v1.z); u.h[7]=f2b(v1.w);
        u.h[8]=f2b(v2.x); u.h[9]=f2b(v2.y); u.h[10]=f2b(v2.z); u.h[11]=f2b(v2.w);
        u.h[12]=f2b(v3.x); u.h[13]=f2b(v3.y); u.h[14]=f2b(v3.z); u.h[15]=f2b(v3.w);
        *(bf16x8*)&xb[row][seg*16]     = u.v[0];
        *(bf16x8*)&xb[row][seg*16 + 8] = u.v[1];
    }
    #pragma unroll
    for (int kk = 0; kk < 4; ++kk) {
        int k = (tid >> 5) + kk * 16;
        int n0 = (tid & 31) * 4;
        float4 wv4 = *(const float4*)(W1 + k * HH + n0);
        W1T[n0+0][k] = f2b(wv4.x); W1T[n0+1][k] = f2b(wv4.y);
        W1T[n0+2][k] = f2b(wv4.z); W1T[n0+3][k] = f2b(wv4.w);
    }
    if (tid < 128) { sb1[tid] = b1[tid]; sb2[tid] = b2[tid]; }
    sbih[tid] = b_ih[tid] + b_hh[tid];
    __syncthreads();

    {
        bf16x8 a0 = ldb(&xb[m0 + lm][lk]);
        bf16x8 a1 = ldb(&xb[m0 + lm][32 + lk]);
        #pragma unroll
        for (int ct = 0; ct < 8; ++ct) {
            bf16x8 bv0 = ldb(&W1T[ct*16 + lm][lk]);
            bf16x8 bv1 = ldb(&W1T[ct*16 + lm][32 + lk]);
            f32x4 acc = {0.f, 0.f, 0.f, 0.f};
            acc = mm16(a0, bv0, acc);
            acc = mm16(a1, bv1, acc);
            float bias = sb1[ct*16 + lm];
            int rb = m0 + (lane >> 4) * 4;
            #pragma unroll
            for (int rr = 0; rr < 4; ++rr)
                h1b[rb + rr][ct*16 + lm] = f2b(fmaxf(acc[rr] + bias, 0.f));
        }
    }
    __syncthreads();

    #pragma unroll
    for (int kk = 0; kk < 8; ++kk) {
        int k = (tid >> 5) + kk * 16;
        int n0 = (tid & 31) * 4;
        float4 wv4 = *(const float4*)(W2 + k * HH + n0);
        W2T[n0+0][k] = f2b(wv4.x); W2T[n0+1][k] = f2b(wv4.y);
        W2T[n0+2][k] = f2b(wv4.z); W2T[n0+3][k] = f2b(wv4.w);
    }
    __syncthreads();

    {
        bf16x8 a[4];
        #pragma unroll
        for (int kt = 0; kt < 4; ++kt) a[kt] = ldb(&h1b[m0 + lm][kt*32 + lk]);
        #pragma unroll
        for (int ct = 0; ct < 8; ++ct) {
            f32x4 acc = {0.f, 0.f, 0.f, 0.f};
            #pragma unroll
            for (int kt = 0; kt < 4; ++kt)
                acc = mm16(a[kt], ldb(&W2T[ct*16 + lm][kt*32 + lk]), acc);
            float bias = sb2[ct*16 + lm];
            int rb = m0 + (lane >> 4) * 4;
            #pragma unroll
            for (int rr = 0; rr < 4; ++rr)
                h2b[rb + rr][ct*16 + lm] = f2b(fmaxf(acc[rr] + bias, 0.f));
        }
    }
    __syncthreads();

    bf16x8 a3[4];
    #pragma unroll
    for (int kt = 0; kt < 4; ++kt) a3[kt] = ldb(&h2b[m0 + lm][kt*32 + lk]);

    for (int jc = 0; jc < 2; ++jc) {
        #pragma unroll
        for (int jj = 0; jj < 4; ++jj) {
            int jrow = jj * 64 + (tid >> 3);
            int seg = tid & 7;
            const float4* ws = (const float4*)(w_ih + (size_t)(jc*256 + jrow) * HH + seg * 16);
            float4 v0 = ws[0], v1 = ws[1], v2 = ws[2], v3 = ws[3];
            union { bf16x8 v[2]; __hip_bfloat16 h[16]; } u;
            u.h[0]=f2b(v0.x); u.h[1]=f2b(v0.y); u.h[2]=f2b(v0.z); u.h[3]=f2b(v0.w);
            u.h[4]=f2b(v1.x); u.h[5]=f2b(v1.y); u.h[6]=f2b(v1.z); u.h[7]=f2b(v1.w);
            u.h[8]=f2b(v2.x); u.h[9]=f2b(v2.y); u.h[10]=f2b(v2.z); u.h[11]=f2b(v2.w);
            u.h[12]=f2b(v3.x); u.h[13]=f2b(v3.y); u.h[14]=f2b(v3.z); u.h[15]=f2b(v3.w);
            *(bf16x8*)&wihb[jrow][seg*16]     = u.v[0];
            *(bf16x8*)&wihb[jrow][seg*16 + 8] = u.v[1];
        }
        __syncthreads();

        #pragma unroll
        for (int ct = 0; ct < 16; ++ct) {
            f32x4 acc = {0.f, 0.f, 0.f, 0.f};
            #pragma unroll
            for (int kt = 0; kt < 4; ++kt)
                acc = mm16(a3[kt], ldb(&wihb[ct*16 + lm][kt*32 + lk]), acc);
            int jcol = jc*256 + ct*16 + lm;          // gate-major index gt*128+un
            float bias = sbih[jcol];
            int cnew = (jcol & 127) * 4 + (jcol >> 7); // gate-interleaved column
            size_t rb = r0 + m0 + (lane >> 4) * 4;
            #pragma unroll
            for (int rr = 0; rr < 4; ++rr)
                xg[(rb + rr) * 512 + cnew] = f2b(acc[rr] + bias);
        }
        __syncthreads();
    }
}

// ---------------------------------------------------------------------------
// Kernel 2: LSTM scan — r10 structure; riders: htile pitch 132 (conflict-free
// b128 B-frag reads) and single bf16x4 xg load per lane per step (gate-
// interleaved xg layout). h_t stored bf16 into the consumed xg row slots
// 0..127 for the heads kernel (safe: that row's gates were prefetched one
// step earlier and the intervening __syncthreads drained the loads).
// ---------------------------------------------------------------------------
__global__ __launch_bounds__(512) void lstm_kernel(
    const __hip_bfloat16* __restrict__ xg,  // [N][128][4] bf16 (bias included)
    __hip_bfloat16* __restrict__ hst,       // alias of xg: h_t -> row n slots 0..127
    const float* __restrict__ w_hh,         // [512,128]
    const int* __restrict__ done,           // [N]
    const float* __restrict__ h0,
    const float* __restrict__ c0,
    float* __restrict__ out)                // lp N | ent N | val N | hN B*H | cN B*H
{
    // pitch 132 bf16 = 66 words; 66 mod 32 = 2 -> the 16 b128-read lanes
    // (stride 1 row) land on banks 2*lm : all distinct -> conflict-free.
    __shared__ __align__(16) __hip_bfloat16 htile[2][16][132];
    __shared__ __align__(16) float scr[8][4][4][16];           // wave transpose

    const int tid  = threadIdx.x;
    const int lane = tid & 63;
    const int w    = tid >> 6;       // wave 0..7
    const int lm   = lane & 15;      // MFMA fragment row/col id
    const int lko  = lane >> 4;      // k-octet 0..3
    const int b0   = blockIdx.x * 4;
    const int b    = lane >> 4;      // gate phase: this lane's batch (0..3)
    const int uo   = lane & 15;      // gate phase: unit offset
    const int un   = w * 16 + uo;    // unit index 0..127

    // ---- A-frags: w_hh rows gt*128 + w*16 + lm ----
    bf16x8 wf[4][4];
    #pragma unroll
    for (int gt = 0; gt < 4; ++gt) {
        #pragma unroll
        for (int kt = 0; kt < 4; ++kt) {
            const float* p = w_hh + (size_t)(gt*128 + w*16 + lm)*HH + kt*32 + lko*8;
            float4 a = *(const float4*)p;
            float4 bq = *(const float4*)(p + 4);
            union { bf16x8 v; __hip_bfloat16 h[8]; } uu;
            uu.h[0]=f2b(a.x); uu.h[1]=f2b(a.y); uu.h[2]=f2b(a.z); uu.h[3]=f2b(a.w);
            uu.h[4]=f2b(bq.x); uu.h[5]=f2b(bq.y); uu.h[6]=f2b(bq.z); uu.h[7]=f2b(bq.w);
            wf[gt][kt] = uu.v;
        }
    }

    // ---- init htile[0] rows 0..3 from h0; rows 4..15 of both buffers = 0 ----
    {
        int r = tid >> 7, uu2 = tid & 127;
        htile[0][r][uu2] = f2b(h0[(size_t)(b0 + r)*HH + uu2]);
        for (int idx = tid; idx < 12*132; idx += 512) {
            (&htile[0][4][0])[idx] = f2b(0.0f);
            (&htile[1][4][0])[idx] = f2b(0.0f);
        }
    }
    // ---- per-lane state: c,h for (batch b, unit un) ----
    float c_reg = c0[(size_t)(b0 + b)*HH + un];
    float h_reg = h0[(size_t)(b0 + b)*HH + un];

    // ---- prefetch operands for it=0 (one 8B load: all 4 gates of unit un) ----
    int dn_c = done[b0 + b];
    bf16x4 xq_c = *(const bf16x4*)(xg + (size_t)(b0 + b)*512 + un*4);

    __syncthreads();

    for (int it = 0; it < TT; ++it) {
        const int cur = it & 1, nxt = cur ^ 1;
        const size_t base = (size_t)it * BB + b0;

        // prefetch operands for it+1 (hidden under the MFMA + gate work)
        int dn_n = 0;
        bf16x4 xq_n = {};
        if (it < TT - 1) {
            const size_t nb = base + BB;
            dn_n = done[nb + b];
            xq_n = *(const bf16x4*)(xg + (nb + b)*512 + un*4);
        }

        // B-frags: raw h_{it-1} from htile[cur]
        bf16x8 hb[4];
        #pragma unroll
        for (int kt = 0; kt < 4; ++kt)
            hb[kt] = ldb(&htile[cur][lm][kt*32 + lko*8]);

        f32x4 acc[4];
        #pragma unroll
        for (int gt = 0; gt < 4; ++gt) acc[gt] = (f32x4){0.f, 0.f, 0.f, 0.f};
        #pragma unroll
        for (int kt = 0; kt < 4; ++kt)
            #pragma unroll
            for (int gt = 0; gt < 4; ++gt)
                acc[gt] = mm16(wf[gt][kt], hb[kt], acc[gt]);

        // wave-local transpose: (col=batch, row=unit) -> (lane = batch,unit)
        if (lm < 4) {
            #pragma unroll
            for (int gt = 0; gt < 4; ++gt)
                *(f32x4*)&scr[w][gt][lm][lko*4] = acc[gt];
        }
        __asm__ volatile("" ::: "memory");  // keep DS order; in-order pipe
        float g4[4];
        #pragma unroll
        for (int gt = 0; gt < 4; ++gt)
            g4[gt] = scr[w][gt][b][uo];

        const float keep = dn_c ? 0.0f : 1.0f;
        float gi = fmaf(g4[0], keep, (float)xq_c[0]);
        float gf = fmaf(g4[1], keep, (float)xq_c[1]);
        float gg = fmaf(g4[2], keep, (float)xq_c[2]);
        float go = fmaf(g4[3], keep, (float)xq_c[3]);
        float cp = c_reg * keep;
        float cn = sigmoidf_(gf) * cp + sigmoidf_(gi) * tanhf_(gg);
        float hn = sigmoidf_(go) * tanhf_(cn);
        c_reg = cn;
        h_reg = hn;
        __hip_bfloat16 hnb = f2b(hn);
        htile[nxt][b][un] = hnb;
        // store h_t (bf16) into the consumed xg row for the heads kernel
        hst[(base + b)*512 + un] = hnb;

        __syncthreads();

        dn_c = dn_n;
        xq_c = xq_n;
    }

    // ---- final states (each lane owns one (b,un) pair) ----
    out[3*(size_t)NN + (size_t)(b0 + b)*HH + un] = h_reg;
    out[3*(size_t)NN + (size_t)BB*HH + (size_t)(b0 + b)*HH + un] = c_reg;
}

// ---------------------------------------------------------------------------
// Kernel 3: fused heads — logits/value GEMM (MFMA) + softmax/entropy/lp.
// 512 threads = 8 waves; wave handles 16 rows; grid = N/128 = 2048 blocks.
// B-frags built from LDS-staged TRANSPOSED Wa (WaT[32][132] bf16) via one
// ds_read_b128 per kt instead of 96 scalar global loads per thread.
// ---------------------------------------------------------------------------
__global__ __launch_bounds__(512) void heads_kernel(
    const __hip_bfloat16* __restrict__ hbuf, // xg base; row n -> hbuf+n*512, 128 bf16
    const int* __restrict__ mask,            // [N,32] bool as int32
    const int* __restrict__ action,          // [N]
    const float* __restrict__ Wa,            // [128,32]
    const float* __restrict__ ba,
    const float* __restrict__ Wc,            // [128]
    const float* __restrict__ bc,
    float* __restrict__ out)
{
    __shared__ __align__(16) __hip_bfloat16 WaT[32][132]; // transposed Wa
    __shared__ __align__(16) __hip_bfloat16 WcB[128];

    const int tid  = threadIdx.x;
    const int lane = tid & 63;
    const int w    = tid >> 6;
    const int lm   = lane & 15;
    const int lko  = lane >> 4;
    const size_t nbase = (size_t)blockIdx.x * 128 + w * 16;

    // stage WaT[j][k] = Wa[k][j] (16KB f32 -> 8.25KB bf16), WcB
    for (int idx = tid; idx < 128*32; idx += 512) {
        int k = idx >> 5, j = idx & 31;
        WaT[j][k] = f2b(Wa[idx]);
    }
    if (tid < 128) WcB[tid] = f2b(Wc[tid]);
    __syncthreads();

    // A-frags: 16 h-rows
    bf16x8 a[4];
    #pragma unroll
    for (int kt = 0; kt < 4; ++kt)
        a[kt] = ldb(hbuf + (nbase + lm)*512 + kt*32 + lko*8);

    // B-frags from LDS: Wa cols lm and 16+lm; Wc in col 0
    bf16x8 wa0[4], wa1[4], wcf[4];
    #pragma unroll
    for (int kt = 0; kt < 4; ++kt) {
        wa0[kt] = ldb(&WaT[lm][kt*32 + lko*8]);
        wa1[kt] = ldb(&WaT[16 + lm][kt*32 + lko*8]);
        bf16x8 z = {};
        wcf[kt] = (lm == 0) ? ldb(&WcB[kt*32 + lko*8]) : z;
    }

    f32x4 t0 = {0.f,0.f,0.f,0.f}, t1 = {0.f,0.f,0.f,0.f}, tv = {0.f,0.f,0.f,0.f};
    #pragma unroll
    for (int kt = 0; kt < 4; ++kt) {
        t0 = mm16(a[kt], wa0[kt], t0);
        t1 = mm16(a[kt], wa1[kt], t1);
        tv = mm16(a[kt], wcf[kt], tv);
    }

    const float ba0 = ba[lm], ba1 = ba[16 + lm], bcv = bc[0];

    #pragma unroll
    for (int r = 0; r < 4; ++r) {
        const size_t n = nbase + lko*4 + r;
        float lg0 = t0[r] + ba0;
        float lg1 = t1[r] + ba1;
        if (mask[n*32 + lm] == 0)      lg0 = -1e8f;
        if (mask[n*32 + 16 + lm] == 0) lg1 = -1e8f;

        float mx = fmaxf(lg0, lg1);
        #pragma unroll
        for (int off = 8; off > 0; off >>= 1)
            mx = fmaxf(mx, __shfl_xor(mx, off, 16));
        float e0 = __expf(lg0 - mx), e1 = __expf(lg1 - mx);
        float s = e0 + e1;
        #pragma unroll
        for (int off = 8; off > 0; off >>= 1)
            s += __shfl_xor(s, off, 16);
        float lse = __logf(s);
        float lp0 = lg0 - mx - lse;
        float lp1 = lg1 - mx - lse;
        float entl = -(e0 * lp0 + e1 * lp1) / s;
        #pragma unroll
        for (int off = 8; off > 0; off >>= 1)
            entl += __shfl_xor(entl, off, 16);

        int act = action[n];
        if (lm == act)      out[n] = lp0;
        if (16 + lm == act) out[n] = lp1;
        if (lm == 0) {
            out[(size_t)NN + n] = entl;
            out[2*(size_t)NN + n] = tv[r] + bcv;
        }
    }
}

extern "C" void kernel_launch(void* const* d_in, const int* in_sizes, int n_in,
                              void* d_out, int out_size, void* d_ws, size_t ws_size,
                              hipStream_t stream) {
    const float* x      = (const float*)d_in[0];
    const int*   done   = (const int*)d_in[1];
    const int*   action = (const int*)d_in[2];
    const int*   mask   = (const int*)d_in[3];
    const float* h0     = (const float*)d_in[4];
    const float* c0     = (const float*)d_in[5];
    const float* W1     = (const float*)d_in[6];
    const float* b1     = (const float*)d_in[7];
    const float* W2     = (const float*)d_in[8];
    const float* b2     = (const float*)d_in[9];
    const float* w_ih   = (const float*)d_in[10];
    const float* w_hh   = (const float*)d_in[11];
    const float* b_ih   = (const float*)d_in[12];
    const float* b_hh   = (const float*)d_in[13];
    const float* Wa     = (const float*)d_in[14];
    const float* ba     = (const float*)d_in[15];
    const float* Wc     = (const float*)d_in[16];
    const float* bc     = (const float*)d_in[17];

    __hip_bfloat16* xg = (__hip_bfloat16*)d_ws;  // [N,512] bf16 = 256 MiB

    trunk_kernel<<<NN/128, 512, 0, stream>>>(x, W1, b1, W2, b2, w_ih, b_ih, b_hh, xg);
    lstm_kernel<<<BB/4, 512, 0, stream>>>(xg, xg, w_hh, done, h0, c0, (float*)d_out);
    heads_kernel<<<NN/128, 512, 0, stream>>>(xg, mask, action, Wa, ba, Wc, bc,
                                             (float*)d_out);
}

// Round 12
// 481.853 us; speedup vs baseline: 1.3506x; 1.3506x over previous
//
#include <hip/hip_runtime.h>
#include <hip/hip_bf16.h>

// Problem constants
#define TT   256
#define BB   1024
#define OBS  64
#define HH   128
#define AA   32
#define NN   (TT*BB)          // 262144

typedef __bf16 bf16x8 __attribute__((ext_vector_type(8)));
typedef __bf16 bf16x4 __attribute__((ext_vector_type(4)));
typedef float  f32x4  __attribute__((ext_vector_type(4)));

__device__ __forceinline__ float sigmoidf_(float x) {
    return 1.0f / (1.0f + __expf(-x));
}
__device__ __forceinline__ float tanhf_(float x) {
    float ax = fabsf(x);
    float e  = __expf(-2.0f * ax);
    float t  = (1.0f - e) / (1.0f + e);
    return copysignf(t, x);
}
__device__ __forceinline__ __hip_bfloat16 f2b(float v) { return __float2bfloat16(v); }
__device__ __forceinline__ bf16x8 ldb(const __hip_bfloat16* p) {
    return *reinterpret_cast<const bf16x8*>(p);
}
__device__ __forceinline__ f32x4 mm16(bf16x8 a, bf16x8 b, f32x4 c) {
    return __builtin_amdgcn_mfma_f32_16x16x32_bf16(a, b, c, 0, 0, 0);
}

// ---------------------------------------------------------------------------
// Kernel 1 (MFMA bf16): hidden = relu(relu(x@W1+b1)@W2+b2);
//   xg = hidden@w_ih.T + (b_ih+b_hh) -> bf16 [N][128][4] (gate-interleaved:
//   column = un*4 + gt, so the LSTM reads all 4 gates of a unit as one 8B load)
// ---------------------------------------------------------------------------
__global__ __launch_bounds__(512) void trunk_kernel(
    const float* __restrict__ x,
    const float* __restrict__ W1, const float* __restrict__ b1,
    const float* __restrict__ W2, const float* __restrict__ b2,
    const float* __restrict__ w_ih,
    const float* __restrict__ b_ih, const float* __restrict__ b_hh,
    __hip_bfloat16* __restrict__ xg)
{
    __shared__ __align__(16) char smem[109568];
    __hip_bfloat16 (*xb)[72]    = (__hip_bfloat16(*)[72])(smem);
    __hip_bfloat16 (*W1T)[72]   = (__hip_bfloat16(*)[72])(smem + 18432);
    __hip_bfloat16 (*W2T)[136]  = (__hip_bfloat16(*)[136])(smem);
    __hip_bfloat16 (*h1b)[136]  = (__hip_bfloat16(*)[136])(smem + 36864);
    __hip_bfloat16 (*h2b)[136]  = (__hip_bfloat16(*)[136])(smem + 71680);
    __hip_bfloat16 (*wihb)[136] = (__hip_bfloat16(*)[136])(smem);
    float* sb1  = (float*)(smem + 106496);
    float* sb2  = sb1 + 128;
    float* sbih = sb2 + 128;

    const int tid  = threadIdx.x;
    const int lane = tid & 63;
    const int w    = tid >> 6;
    const int m0   = w * 16;
    const int lm   = lane & 15;
    const int lk   = (lane >> 4) * 8;
    const size_t r0 = (size_t)blockIdx.x * 128;

    {
        int row = tid >> 2, seg = tid & 3;
        const float4* xs = (const float4*)(x + (r0 + row) * OBS + seg * 16);
        float4 v0 = xs[0], v1 = xs[1], v2 = xs[2], v3 = xs[3];
        union { bf16x8 v[2]; __hip_bfloat16 h[16]; } u;
        u.h[0]=f2b(v0.x); u.h[1]=f2b(v0.y); u.h[2]=f2b(v0.z); u.h[3]=f2b(v0.w);
        u.h[4]=f2b(v1.x); u.h[5]=f2b(v1.y); u.h[6]=f2b(v1.z); u.h[7]=f2b(v1.w);
        u.h[8]=f2b(v2.x); u.h[9]=f2b(v2.y); u.h[10]=f2b(v2.z); u.h[11]=f2b(v2.w);
        u.h[12]=f2b(v3.x); u.h[13]=f2b(v3.y); u.h[14]=f2b(v3.z); u.h[15]=f2b(v3.w);
        *(bf16x8*)&xb[row][seg*16]     = u.v[0];
        *(bf16x8*)&xb[row][seg*16 + 8] = u.v[1];
    }
    #pragma unroll
    for (int kk = 0; kk < 4; ++kk) {
        int k = (tid >> 5) + kk * 16;
        int n0 = (tid & 31) * 4;
        float4 wv4 = *(const float4*)(W1 + k * HH + n0);
        W1T[n0+0][k] = f2b(wv4.x); W1T[n0+1][k] = f2b(wv4.y);
        W1T[n0+2][k] = f2b(wv4.z); W1T[n0+3][k] = f2b(wv4.w);
    }
    if (tid < 128) { sb1[tid] = b1[tid]; sb2[tid] = b2[tid]; }
    sbih[tid] = b_ih[tid] + b_hh[tid];
    __syncthreads();

    {
        bf16x8 a0 = ldb(&xb[m0 + lm][lk]);
        bf16x8 a1 = ldb(&xb[m0 + lm][32 + lk]);
        #pragma unroll
        for (int ct = 0; ct < 8; ++ct) {
            bf16x8 bv0 = ldb(&W1T[ct*16 + lm][lk]);
            bf16x8 bv1 = ldb(&W1T[ct*16 + lm][32 + lk]);
            f32x4 acc = {0.f, 0.f, 0.f, 0.f};
            acc = mm16(a0, bv0, acc);
            acc = mm16(a1, bv1, acc);
            float bias = sb1[ct*16 + lm];
            int rb = m0 + (lane >> 4) * 4;
            #pragma unroll
            for (int rr = 0; rr < 4; ++rr)
                h1b[rb + rr][ct*16 + lm] = f2b(fmaxf(acc[rr] + bias, 0.f));
        }
    }
    __syncthreads();

    #pragma unroll
    for (int kk = 0; kk < 8; ++kk) {
        int k = (tid >> 5) + kk * 16;
        int n0 = (tid & 31) * 4;
        float4 wv4 = *(const float4*)(W2 + k * HH + n0);
        W2T[n0+0][k] = f2b(wv4.x); W2T[n0+1][k] = f2b(wv4.y);
        W2T[n0+2][k] = f2b(wv4.z); W2T[n0+3][k] = f2b(wv4.w);
    }
    __syncthreads();

    {
        bf16x8 a[4];
        #pragma unroll
        for (int kt = 0; kt < 4; ++kt) a[kt] = ldb(&h1b[m0 + lm][kt*32 + lk]);
        #pragma unroll
        for (int ct = 0; ct < 8; ++ct) {
            f32x4 acc = {0.f, 0.f, 0.f, 0.f};
            #pragma unroll
            for (int kt = 0; kt < 4; ++kt)
                acc = mm16(a[kt], ldb(&W2T[ct*16 + lm][kt*32 + lk]), acc);
            float bias = sb2[ct*16 + lm];
            int rb = m0 + (lane >> 4) * 4;
            #pragma unroll
            for (int rr = 0; rr < 4; ++rr)
                h2b[rb + rr][ct*16 + lm] = f2b(fmaxf(acc[rr] + bias, 0.f));
        }
    }
    __syncthreads();

    bf16x8 a3[4];
    #pragma unroll
    for (int kt = 0; kt < 4; ++kt) a3[kt] = ldb(&h2b[m0 + lm][kt*32 + lk]);

    for (int jc = 0; jc < 2; ++jc) {
        #pragma unroll
        for (int jj = 0; jj < 4; ++jj) {
            int jrow = jj * 64 + (tid >> 3);
            int seg = tid & 7;
            const float4* ws = (const float4*)(w_ih + (size_t)(jc*256 + jrow) * HH + seg * 16);
            float4 v0 = ws[0], v1 = ws[1], v2 = ws[2], v3 = ws[3];
            union { bf16x8 v[2]; __hip_bfloat16 h[16]; } u;
            u.h[0]=f2b(v0.x); u.h[1]=f2b(v0.y); u.h[2]=f2b(v0.z); u.h[3]=f2b(v0.w);
            u.h[4]=f2b(v1.x); u.h[5]=f2b(v1.y); u.h[6]=f2b(v1.z); u.h[7]=f2b(v1.w);
            u.h[8]=f2b(v2.x); u.h[9]=f2b(v2.y); u.h[10]=f2b(v2.z); u.h[11]=f2b(v2.w);
            u.h[12]=f2b(v3.x); u.h[13]=f2b(v3.y); u.h[14]=f2b(v3.z); u.h[15]=f2b(v3.w);
            *(bf16x8*)&wihb[jrow][seg*16]     = u.v[0];
            *(bf16x8*)&wihb[jrow][seg*16 + 8] = u.v[1];
        }
        __syncthreads();

        #pragma unroll
        for (int ct = 0; ct < 16; ++ct) {
            f32x4 acc = {0.f, 0.f, 0.f, 0.f};
            #pragma unroll
            for (int kt = 0; kt < 4; ++kt)
                acc = mm16(a3[kt], ldb(&wihb[ct*16 + lm][kt*32 + lk]), acc);
            int jcol = jc*256 + ct*16 + lm;          // gate-major index gt*128+un
            float bias = sbih[jcol];
            int cnew = (jcol & 127) * 4 + (jcol >> 7); // gate-interleaved column
            size_t rb = r0 + m0 + (lane >> 4) * 4;
            #pragma unroll
            for (int rr = 0; rr < 4; ++rr)
                xg[(rb + rr) * 512 + cnew] = f2b(acc[rr] + bias);
        }
        __syncthreads();
    }
}

// ---------------------------------------------------------------------------
// Kernel 2: LSTM scan — r10 structure (pitch 136: 272B rows, 16B-ALIGNED
// b128 reads, 2-way bank alias which is free). Only delta vs r10: the xg
// prefetch is ONE bf16x4 (8B) load per lane (gate-interleaved layout)
// instead of 4 scalar 2B loads. h_t stored bf16 into the consumed xg row
// slots 0..127 for the heads kernel (safe: that row's gates were prefetched
// one step earlier; the intervening __syncthreads drained the loads).
// ---------------------------------------------------------------------------
__global__ __launch_bounds__(512) void lstm_kernel(
    const __hip_bfloat16* __restrict__ xg,  // [N][128][4] bf16 (bias included)
    __hip_bfloat16* __restrict__ hst,       // alias of xg: h_t -> row n slots 0..127
    const float* __restrict__ w_hh,         // [512,128]
    const int* __restrict__ done,           // [N]
    const float* __restrict__ h0,
    const float* __restrict__ c0,
    float* __restrict__ out)                // lp N | ent N | val N | hN B*H | cN B*H
{
    __shared__ __align__(16) __hip_bfloat16 htile[2][16][136]; // raw h (bf16)
    __shared__ __align__(16) float scr[8][4][4][16];           // wave transpose

    const int tid  = threadIdx.x;
    const int lane = tid & 63;
    const int w    = tid >> 6;       // wave 0..7
    const int lm   = lane & 15;      // MFMA fragment row/col id
    const int lko  = lane >> 4;      // k-octet 0..3
    const int b0   = blockIdx.x * 4;
    const int b    = lane >> 4;      // gate phase: this lane's batch (0..3)
    const int uo   = lane & 15;      // gate phase: unit offset
    const int un   = w * 16 + uo;    // unit index 0..127

    // ---- A-frags: w_hh rows gt*128 + w*16 + lm ----
    bf16x8 wf[4][4];
    #pragma unroll
    for (int gt = 0; gt < 4; ++gt) {
        #pragma unroll
        for (int kt = 0; kt < 4; ++kt) {
            const float* p = w_hh + (size_t)(gt*128 + w*16 + lm)*HH + kt*32 + lko*8;
            float4 a = *(const float4*)p;
            float4 bq = *(const float4*)(p + 4);
            union { bf16x8 v; __hip_bfloat16 h[8]; } uu;
            uu.h[0]=f2b(a.x); uu.h[1]=f2b(a.y); uu.h[2]=f2b(a.z); uu.h[3]=f2b(a.w);
            uu.h[4]=f2b(bq.x); uu.h[5]=f2b(bq.y); uu.h[6]=f2b(bq.z); uu.h[7]=f2b(bq.w);
            wf[gt][kt] = uu.v;
        }
    }

    // ---- init htile[0] rows 0..3 from h0; rows 4..15 of both buffers = 0 ----
    {
        int r = tid >> 7, uu2 = tid & 127;
        htile[0][r][uu2] = f2b(h0[(size_t)(b0 + r)*HH + uu2]);
        for (int idx = tid; idx < 12*136; idx += 512) {
            (&htile[0][4][0])[idx] = f2b(0.0f);
            (&htile[1][4][0])[idx] = f2b(0.0f);
        }
    }
    // ---- per-lane state: c,h for (batch b, unit un) ----
    float c_reg = c0[(size_t)(b0 + b)*HH + un];
    float h_reg = h0[(size_t)(b0 + b)*HH + un];

    // ---- prefetch operands for it=0 (one 8B load: all 4 gates of unit un) ----
    int dn_c = done[b0 + b];
    bf16x4 xq_c = *(const bf16x4*)(xg + (size_t)(b0 + b)*512 + un*4);

    __syncthreads();

    for (int it = 0; it < TT; ++it) {
        const int cur = it & 1, nxt = cur ^ 1;
        const size_t base = (size_t)it * BB + b0;

        // prefetch operands for it+1 (hidden under the MFMA + gate work)
        int dn_n = 0;
        bf16x4 xq_n = {};
        if (it < TT - 1) {
            const size_t nb = base + BB;
            dn_n = done[nb + b];
            xq_n = *(const bf16x4*)(xg + (nb + b)*512 + un*4);
        }

        // B-frags: raw h_{it-1} from htile[cur]
        bf16x8 hb[4];
        #pragma unroll
        for (int kt = 0; kt < 4; ++kt)
            hb[kt] = ldb(&htile[cur][lm][kt*32 + lko*8]);

        f32x4 acc[4];
        #pragma unroll
        for (int gt = 0; gt < 4; ++gt) acc[gt] = (f32x4){0.f, 0.f, 0.f, 0.f};
        #pragma unroll
        for (int kt = 0; kt < 4; ++kt)
            #pragma unroll
            for (int gt = 0; gt < 4; ++gt)
                acc[gt] = mm16(wf[gt][kt], hb[kt], acc[gt]);

        // wave-local transpose: (col=batch, row=unit) -> (lane = batch,unit)
        if (lm < 4) {
            #pragma unroll
            for (int gt = 0; gt < 4; ++gt)
                *(f32x4*)&scr[w][gt][lm][lko*4] = acc[gt];
        }
        __asm__ volatile("" ::: "memory");  // keep DS order; in-order pipe
        float g4[4];
        #pragma unroll
        for (int gt = 0; gt < 4; ++gt)
            g4[gt] = scr[w][gt][b][uo];

        const float keep = dn_c ? 0.0f : 1.0f;
        float gi = fmaf(g4[0], keep, (float)xq_c[0]);
        float gf = fmaf(g4[1], keep, (float)xq_c[1]);
        float gg = fmaf(g4[2], keep, (float)xq_c[2]);
        float go = fmaf(g4[3], keep, (float)xq_c[3]);
        float cp = c_reg * keep;
        float cn = sigmoidf_(gf) * cp + sigmoidf_(gi) * tanhf_(gg);
        float hn = sigmoidf_(go) * tanhf_(cn);
        c_reg = cn;
        h_reg = hn;
        __hip_bfloat16 hnb = f2b(hn);
        htile[nxt][b][un] = hnb;
        // store h_t (bf16) into the consumed xg row for the heads kernel
        hst[(base + b)*512 + un] = hnb;

        __syncthreads();

        dn_c = dn_n;
        xq_c = xq_n;
    }

    // ---- final states (each lane owns one (b,un) pair) ----
    out[3*(size_t)NN + (size_t)(b0 + b)*HH + un] = h_reg;
    out[3*(size_t)NN + (size_t)BB*HH + (size_t)(b0 + b)*HH + un] = c_reg;
}

// ---------------------------------------------------------------------------
// Kernel 3: fused heads — logits/value GEMM (MFMA) + softmax/entropy/lp.
// 512 blocks x 512 threads; each block processes 4 row-tiles of 128 rows
// (amortizes the WaT/WcB LDS staging and launch overhead). B-frags from
// LDS-staged transposed Wa (WaT[32][136] bf16, 16B-aligned rows).
// ---------------------------------------------------------------------------
__global__ __launch_bounds__(512) void heads_kernel(
    const __hip_bfloat16* __restrict__ hbuf, // xg base; row n -> hbuf+n*512, 128 bf16
    const int* __restrict__ mask,            // [N,32] bool as int32
    const int* __restrict__ action,          // [N]
    const float* __restrict__ Wa,            // [128,32]
    const float* __restrict__ ba,
    const float* __restrict__ Wc,            // [128]
    const float* __restrict__ bc,
    float* __restrict__ out)
{
    __shared__ __align__(16) __hip_bfloat16 WaT[32][136]; // transposed Wa
    __shared__ __align__(16) __hip_bfloat16 WcB[128];

    const int tid  = threadIdx.x;
    const int lane = tid & 63;
    const int w    = tid >> 6;
    const int lm   = lane & 15;
    const int lko  = lane >> 4;

    // stage WaT[j][k] = Wa[k][j], WcB (once per block)
    for (int idx = tid; idx < 128*32; idx += 512) {
        int k = idx >> 5, j = idx & 31;
        WaT[j][k] = f2b(Wa[idx]);
    }
    if (tid < 128) WcB[tid] = f2b(Wc[tid]);
    __syncthreads();

    // B-frags from LDS: Wa cols lm and 16+lm; Wc in col 0
    bf16x8 wa0[4], wa1[4], wcf[4];
    #pragma unroll
    for (int kt = 0; kt < 4; ++kt) {
        wa0[kt] = ldb(&WaT[lm][kt*32 + lko*8]);
        wa1[kt] = ldb(&WaT[16 + lm][kt*32 + lko*8]);
        bf16x8 z = {};
        wcf[kt] = (lm == 0) ? ldb(&WcB[kt*32 + lko*8]) : z;
    }
    const float ba0 = ba[lm], ba1 = ba[16 + lm], bcv = bc[0];

    #pragma unroll 1
    for (int rt = 0; rt < 4; ++rt) {
        const size_t nbase = (size_t)blockIdx.x * 512 + rt * 128 + w * 16;

        // A-frags: 16 h-rows
        bf16x8 a[4];
        #pragma unroll
        for (int kt = 0; kt < 4; ++kt)
            a[kt] = ldb(hbuf + (nbase + lm)*512 + kt*32 + lko*8);

        f32x4 t0 = {0.f,0.f,0.f,0.f}, t1 = {0.f,0.f,0.f,0.f}, tv = {0.f,0.f,0.f,0.f};
        #pragma unroll
        for (int kt = 0; kt < 4; ++kt) {
            t0 = mm16(a[kt], wa0[kt], t0);
            t1 = mm16(a[kt], wa1[kt], t1);
            tv = mm16(a[kt], wcf[kt], tv);
        }

        #pragma unroll
        for (int r = 0; r < 4; ++r) {
            const size_t n = nbase + lko*4 + r;
            float lg0 = t0[r] + ba0;
            float lg1 = t1[r] + ba1;
            if (mask[n*32 + lm] == 0)      lg0 = -1e8f;
            if (mask[n*32 + 16 + lm] == 0) lg1 = -1e8f;

            float mx = fmaxf(lg0, lg1);
            #pragma unroll
            for (int off = 8; off > 0; off >>= 1)
                mx = fmaxf(mx, __shfl_xor(mx, off, 16));
            float e0 = __expf(lg0 - mx), e1 = __expf(lg1 - mx);
            float s = e0 + e1;
            #pragma unroll
            for (int off = 8; off > 0; off >>= 1)
                s += __shfl_xor(s, off, 16);
            float lse = __logf(s);
            float lp0 = lg0 - mx - lse;
            float lp1 = lg1 - mx - lse;
            float entl = -(e0 * lp0 + e1 * lp1) / s;
            #pragma unroll
            for (int off = 8; off > 0; off >>= 1)
                entl += __shfl_xor(entl, off, 16);

            int act = action[n];
            if (lm == act)      out[n] = lp0;
            if (16 + lm == act) out[n] = lp1;
            if (lm == 0) {
                out[(size_t)NN + n] = entl;
                out[2*(size_t)NN + n] = tv[r] + bcv;
            }
        }
    }
}

extern "C" void kernel_launch(void* const* d_in, const int* in_sizes, int n_in,
                              void* d_out, int out_size, void* d_ws, size_t ws_size,
                              hipStream_t stream) {
    const float* x      = (const float*)d_in[0];
    const int*   done   = (const int*)d_in[1];
    const int*   action = (const int*)d_in[2];
    const int*   mask   = (const int*)d_in[3];
    const float* h0     = (const float*)d_in[4];
    const float* c0     = (const float*)d_in[5];
    const float* W1     = (const float*)d_in[6];
    const float* b1     = (const float*)d_in[7];
    const float* W2     = (const float*)d_in[8];
    const float* b2     = (const float*)d_in[9];
    const float* w_ih   = (const float*)d_in[10];
    const float* w_hh   = (const float*)d_in[11];
    const float* b_ih   = (const float*)d_in[12];
    const float* b_hh   = (const float*)d_in[13];
    const float* Wa     = (const float*)d_in[14];
    const float* ba     = (const float*)d_in[15];
    const float* Wc     = (const float*)d_in[16];
    const float* bc     = (const float*)d_in[17];

    __hip_bfloat16* xg = (__hip_bfloat16*)d_ws;  // [N,512] bf16 = 256 MiB

    trunk_kernel<<<NN/128, 512, 0, stream>>>(x, W1, b1, W2, b2, w_ih, b_ih, b_hh, xg);
    lstm_kernel<<<BB/4, 512, 0, stream>>>(xg, xg, w_hh, done, h0, c0, (float*)d_out);
    heads_kernel<<<NN/512, 512, 0, stream>>>(xg, mask, action, Wa, ba, Wc, bc,
                                             (float*)d_out);
}